// Round 11
// baseline (719.053 us; speedup 1.0000x reference)
//
#include <hip/hip_runtime.h>

#define N_NODES 100000
#define E_EDGES 1000000
#define F_IN    128
#define HID     64
#define OUT_F   40
#define LAYERS  4
#define ALPHA   0.5f
#define BN_EPS  1e-5f

#define SCAN_BLOCKS ((N_NODES + 255) / 256)   // 391
#define TILE_BLOCKS ((N_NODES + 63) / 64)     // 1563

typedef __attribute__((ext_vector_type(8))) short short8;
typedef __attribute__((ext_vector_type(4))) float f32x4;
typedef __attribute__((ext_vector_type(8))) unsigned short ushort8v;

__device__ inline unsigned short f2bf(float f) {
    union { float f; unsigned u; } v; v.f = f;
    unsigned r = v.u + 0x7FFFu + ((v.u >> 16) & 1u);   // RNE
    return (unsigned short)(r >> 16);
}
__device__ inline float bf2f(unsigned short s) {
    union { unsigned u; float f; } v; v.u = ((unsigned)s) << 16;
    return v.f;
}

// ---------- CSR build ----------
__global__ __launch_bounds__(256) void k_deg_count(const int* __restrict__ col,
                                                   int* __restrict__ degInt) {
    int e = blockIdx.x * 256 + threadIdx.x;
    if (e < E_EDGES) atomicAdd(&degInt[col[e]], 1);
}

__global__ __launch_bounds__(256) void k_scanA(const int* __restrict__ degInt,
                                               int* __restrict__ tmpIncl,
                                               int* __restrict__ blockSums) {
    __shared__ int sm[256];
    int i = blockIdx.x * 256 + threadIdx.x;
    int v = (i < N_NODES) ? degInt[i] : 0;
    sm[threadIdx.x] = v;
    __syncthreads();
    for (int d = 1; d < 256; d <<= 1) {
        int t = (threadIdx.x >= d) ? sm[threadIdx.x - d] : 0;
        __syncthreads();
        sm[threadIdx.x] += t;
        __syncthreads();
    }
    if (i < N_NODES) tmpIncl[i] = sm[threadIdx.x];
    if (threadIdx.x == 255) blockSums[blockIdx.x] = sm[255];
}

__global__ __launch_bounds__(512) void k_scanB(int* __restrict__ blockSums,
                                               int* __restrict__ blockOff) {
    __shared__ int sm[512];
    int t = threadIdx.x;
    int v = (t < SCAN_BLOCKS) ? blockSums[t] : 0;
    sm[t] = v;
    __syncthreads();
    for (int d = 1; d < 512; d <<= 1) {
        int u = (t >= d) ? sm[t - d] : 0;
        __syncthreads();
        sm[t] += u;
        __syncthreads();
    }
    if (t < SCAN_BLOCKS) blockOff[t] = sm[t] - v;   // exclusive
}

__global__ __launch_bounds__(256) void k_scanC(const int* __restrict__ degInt,
                                               const int* __restrict__ tmpIncl,
                                               const int* __restrict__ blockOff,
                                               int* __restrict__ rowOff,
                                               int* __restrict__ cursor,
                                               float* __restrict__ dinv) {
    int i = blockIdx.x * 256 + threadIdx.x;
    if (i >= N_NODES) return;
    int d = degInt[i];
    int incl = tmpIncl[i] + blockOff[blockIdx.x];
    int excl = incl - d;
    rowOff[i] = excl;
    cursor[i] = excl;
    dinv[i] = rsqrtf((float)(d + 1));               // +1 self loop
    if (i == N_NODES - 1) rowOff[N_NODES] = incl;   // == E
}

__global__ __launch_bounds__(256) void k_fill(const int* __restrict__ ei,
                                              int* __restrict__ cursor,
                                              int* __restrict__ srow) {
    int e = blockIdx.x * 256 + threadIdx.x;
    if (e >= E_EDGES) return;
    int r = ei[e];
    int c = ei[E_EDGES + e];
    int pos = atomicAdd(&cursor[c], 1);
    srow[pos] = r;
}

// ---------- input layer (MFMA): h = relu(x @ Wi + bi) -> h0bf (bf16), hprev (f32) ----------
__global__ __launch_bounds__(256) void k_input(const float* __restrict__ x,
                                               const float* __restrict__ Wi,
                                               const float* __restrict__ bi,
                                               unsigned short* __restrict__ h0bf,
                                               float* __restrict__ hprev) {
    __shared__ __align__(16) unsigned short xb[64 * 136];    // 17.4 KB
    __shared__ __align__(16) unsigned short wib[64 * 136];   // Wi^T bf16
    __shared__ float bis[64];
    const int tid = threadIdx.x;
    const int n0 = blockIdx.x * 64;
    const int nvalid = min(64, N_NODES - n0);

    if (tid < 64) bis[tid] = bi[tid];
    // stage Wi transposed: wib[j][k] = Wi[k*64+j]
    for (int i = tid; i < F_IN * HID; i += 256) {
        int k = i >> 6, j = i & 63;
        wib[j * 136 + k] = f2bf(Wi[i]);
    }
    // stage x tile rows (bf16)
    for (int i = tid; i < 64 * F_IN; i += 256) {
        int node = i >> 7, k = i & 127;
        float v = (node < nvalid) ? x[(size_t)(n0 + node) * F_IN + k] : 0.0f;
        xb[node * 136 + k] = f2bf(v);
    }
    __syncthreads();

    const int lane = tid & 63, wid = tid >> 6;
    const int ml = lane & 15, gl = lane >> 4;
    const int r0 = wid * 16;

    short8 A[4];
    #pragma unroll
    for (int ks = 0; ks < 4; ++ks)
        A[ks] = *(const short8*)&xb[(r0 + ml) * 136 + ks * 32 + gl * 8];

    #pragma unroll
    for (int ct = 0; ct < 4; ++ct) {
        f32x4 z = {0.f, 0.f, 0.f, 0.f};
        #pragma unroll
        for (int ks = 0; ks < 4; ++ks) {
            short8 b = *(const short8*)&wib[(ct * 16 + ml) * 136 + ks * 32 + gl * 8];
            z = __builtin_amdgcn_mfma_f32_16x16x32_bf16(A[ks], b, z, 0, 0, 0);
        }
        #pragma unroll
        for (int reg = 0; reg < 4; ++reg) {
            int node = n0 + r0 + gl * 4 + reg;
            if (node < N_NODES) {
                int col = ct * 16 + ml;
                float h = fmaxf(z[reg] + bis[col], 0.0f);
                int gidx = node * HID + col;
                h0bf[gidx]  = f2bf(h);
                hprev[gidx] = h;
            }
        }
    }
}

// ---------- per-layer dense part, MFMA. Block = 64 nodes. ----------
__global__ __launch_bounds__(256) void k_layerA(float* __restrict__ hprev,
                                                const unsigned short* __restrict__ h0bf,
                                                float* __restrict__ agg,
                                                const float* __restrict__ sums_prev,
                                                const float* __restrict__ gamma,
                                                const float* __restrict__ beta,
                                                int apply_bn,
                                                const float* __restrict__ w1g,
                                                const float* __restrict__ w2g,
                                                const float* __restrict__ dinv,
                                                unsigned short* __restrict__ sscaled) {
    __shared__ float hp_lds[64 * 68];                       // stride 68 (17.4 KB)
    __shared__ __align__(16) unsigned short wt1[64 * 72];   // W1^T bf16 (9.2 KB)
    __shared__ __align__(16) unsigned short wt2[64 * 72];
    const int tid = threadIdx.x;
    const int n0 = blockIdx.x * 64;

    for (int i = tid; i < HID * HID; i += 256) {
        int k = i >> 6, j = i & 63;
        wt1[j * 72 + k] = f2bf(w1g[i]);
        wt2[j * 72 + k] = f2bf(w2g[i]);
    }

    const int feat = tid & 63;
    const float invN = 1.0f / (float)N_NODES;
    float m = 0.f, inv = 0.f, gam = 0.f, bet = 0.f;
    if (apply_bn) {
        float mm = sums_prev[feat] * invN;
        float vv = sums_prev[HID + feat] * invN - mm * mm;
        m = mm; inv = rsqrtf(vv + BN_EPS);
        gam = gamma[feat]; bet = beta[feat];
    }
    const int nvalid = min(64, N_NODES - n0);
    for (int idx = tid; idx < 64 * HID; idx += 256) {
        int node = idx >> 6;
        float hp = 0.0f;
        if (node < nvalid) {
            int g = (n0 + node) * HID + feat;
            hp = hprev[g];
            if (apply_bn) {
                float a = agg[g];
                hp += fmaxf(gam * (a - m) * inv + bet, 0.0f);
                hprev[g] = hp;
            }
        }
        hp_lds[node * 68 + feat] = hp;
    }
    __syncthreads();

    const int lane = tid & 63, wid = tid >> 6;
    const int ml = lane & 15, gl = lane >> 4;
    const int r0 = wid * 16;

    short8 A1[2], A2[2];
    #pragma unroll
    for (int ks = 0; ks < 2; ++ks) {
        const f32x4* p = (const f32x4*)&hp_lds[(r0 + ml) * 68 + ks * 32 + gl * 8];
        f32x4 x0 = p[0], x1 = p[1];
        short8 fr;
        fr[0] = f2bf(x0[0]); fr[1] = f2bf(x0[1]); fr[2] = f2bf(x0[2]); fr[3] = f2bf(x0[3]);
        fr[4] = f2bf(x1[0]); fr[5] = f2bf(x1[1]); fr[6] = f2bf(x1[2]); fr[7] = f2bf(x1[3]);
        A1[ks] = fr;
        A2[ks] = *(const short8*)&h0bf[(size_t)(n0 + r0 + ml) * HID + ks * 32 + gl * 8];
    }

    f32x4 acc1[4], acc2[4];
    #pragma unroll
    for (int ct = 0; ct < 4; ++ct) {
        short8 b10 = *(const short8*)&wt1[(ct * 16 + ml) * 72 + gl * 8];
        short8 b11 = *(const short8*)&wt1[(ct * 16 + ml) * 72 + 32 + gl * 8];
        short8 b20 = *(const short8*)&wt2[(ct * 16 + ml) * 72 + gl * 8];
        short8 b21 = *(const short8*)&wt2[(ct * 16 + ml) * 72 + 32 + gl * 8];
        f32x4 z = {0.f, 0.f, 0.f, 0.f};
        z = __builtin_amdgcn_mfma_f32_16x16x32_bf16(A1[0], b10, z, 0, 0, 0);
        z = __builtin_amdgcn_mfma_f32_16x16x32_bf16(A1[1], b11, z, 0, 0, 0);
        acc1[ct] = z;
        f32x4 y = {0.f, 0.f, 0.f, 0.f};
        y = __builtin_amdgcn_mfma_f32_16x16x32_bf16(A2[0], b20, y, 0, 0, 0);
        y = __builtin_amdgcn_mfma_f32_16x16x32_bf16(A2[1], b21, y, 0, 0, 0);
        acc2[ct] = y;
    }

    #pragma unroll
    for (int reg = 0; reg < 4; ++reg) {
        int i = gl * 4 + reg;
        int node = n0 + r0 + i;
        if (node < N_NODES) {
            float dv = dinv[node];
            #pragma unroll
            for (int ct = 0; ct < 4; ++ct) {
                int col = ct * 16 + ml;
                int gidx = node * HID + col;
                float hp = hp_lds[(r0 + i) * 68 + col];
                float hz = bf2f(h0bf[gidx]);
                float s   = hp + acc1[ct][reg];
                float ini = ALPHA * hz + acc2[ct][reg];
                float ss  = dv * s;
                sscaled[gidx] = f2bf(ss);
                agg[gidx] = ini + dv * ss;
            }
        }
    }
}

// ---------- gather aggregation + fused BN statistics ----------
// 8-lane group per node; lane ml covers features [8ml, 8ml+8) via ushort8 loads.
// 8 independent nodes per wave, unroll x2 -> 16 rows in flight; no shuffles,
// no idle lanes; per-lane coalesced agg RMW. Stats via LDS atomics.
__global__ __launch_bounds__(256) void k_gather(const int* __restrict__ rowOff,
                                                const int* __restrict__ srow,
                                                const float* __restrict__ dinv,
                                                const unsigned short* __restrict__ sscaled,
                                                float* __restrict__ agg,
                                                float* __restrict__ sums) {
    __shared__ float lsum[HID];
    __shared__ float lqsum[HID];
    const int tid = threadIdx.x;
    if (tid < HID) { lsum[tid] = 0.0f; lqsum[tid] = 0.0f; }
    __syncthreads();

    const int ml = tid & 7;                               // feature octet
    const int gid = (blockIdx.x * 256 + tid) >> 3;        // global group id
    const int ngrp = (gridDim.x * 256) >> 3;              // total groups
    f32x4 s0 = {0.f,0.f,0.f,0.f}, s1 = {0.f,0.f,0.f,0.f};
    f32x4 q0 = {0.f,0.f,0.f,0.f}, q1 = {0.f,0.f,0.f,0.f};

    for (int n = gid; n < N_NODES; n += ngrp) {
        int o0 = rowOff[n], o1 = rowOff[n + 1];
        f32x4 aA0 = {0.f,0.f,0.f,0.f}, aA1 = {0.f,0.f,0.f,0.f};
        f32x4 aB0 = {0.f,0.f,0.f,0.f}, aB1 = {0.f,0.f,0.f,0.f};
        int e = o0;
        for (; e + 2 <= o1; e += 2) {                     // 2 rows in flight per group
            int r0 = srow[e], r1 = srow[e + 1];
            ushort8v a = *(const ushort8v*)&sscaled[(size_t)r0 * HID + ml * 8];
            ushort8v b = *(const ushort8v*)&sscaled[(size_t)r1 * HID + ml * 8];
            aA0[0] += bf2f(a[0]); aA0[1] += bf2f(a[1]); aA0[2] += bf2f(a[2]); aA0[3] += bf2f(a[3]);
            aA1[0] += bf2f(a[4]); aA1[1] += bf2f(a[5]); aA1[2] += bf2f(a[6]); aA1[3] += bf2f(a[7]);
            aB0[0] += bf2f(b[0]); aB0[1] += bf2f(b[1]); aB0[2] += bf2f(b[2]); aB0[3] += bf2f(b[3]);
            aB1[0] += bf2f(b[4]); aB1[1] += bf2f(b[5]); aB1[2] += bf2f(b[6]); aB1[3] += bf2f(b[7]);
        }
        if (e < o1) {
            int r = srow[e];
            ushort8v a = *(const ushort8v*)&sscaled[(size_t)r * HID + ml * 8];
            aA0[0] += bf2f(a[0]); aA0[1] += bf2f(a[1]); aA0[2] += bf2f(a[2]); aA0[3] += bf2f(a[3]);
            aA1[0] += bf2f(a[4]); aA1[1] += bf2f(a[5]); aA1[2] += bf2f(a[6]); aA1[3] += bf2f(a[7]);
        }
        float dv = dinv[n];
        float* ap = &agg[(size_t)n * HID + ml * 8];
        f32x4 x0 = *(const f32x4*)ap;
        f32x4 x1 = *(const f32x4*)(ap + 4);
        #pragma unroll
        for (int j = 0; j < 4; ++j) {
            x0[j] += dv * (aA0[j] + aB0[j]);
            x1[j] += dv * (aA1[j] + aB1[j]);
        }
        *(f32x4*)ap = x0;
        *(f32x4*)(ap + 4) = x1;
        #pragma unroll
        for (int j = 0; j < 4; ++j) {
            s0[j] += x0[j];  q0[j] = fmaf(x0[j], x0[j], q0[j]);
            s1[j] += x1[j];  q1[j] = fmaf(x1[j], x1[j], q1[j]);
        }
    }

    // block-level stats: LDS atomics (per-thread 16 adds), then 128 global atomics
    #pragma unroll
    for (int j = 0; j < 4; ++j) {
        atomicAdd(&lsum[ml * 8 + j], s0[j]);
        atomicAdd(&lsum[ml * 8 + 4 + j], s1[j]);
        atomicAdd(&lqsum[ml * 8 + j], q0[j]);
        atomicAdd(&lqsum[ml * 8 + 4 + j], q1[j]);
    }
    __syncthreads();
    if (tid < HID) {
        atomicAdd(&sums[tid], lsum[tid]);
        atomicAdd(&sums[HID + tid], lqsum[tid]);
    }
}

// ---------- output (MFMA): h = hprev + relu(bn3(agg)); out = h @ Wo + bo ----------
__global__ __launch_bounds__(256) void k_out(const float* __restrict__ hprev,
                                             const float* __restrict__ agg,
                                             const float* __restrict__ sums,
                                             const float* __restrict__ gamma,
                                             const float* __restrict__ beta,
                                             const float* __restrict__ Wo,
                                             const float* __restrict__ bo,
                                             float* __restrict__ out) {
    __shared__ __align__(16) unsigned short hb[64 * 72];    // 9.2 KB
    __shared__ __align__(16) unsigned short wot[48 * 72];   // Wo^T bf16, cols padded to 48
    __shared__ float bos[48];
    const int tid = threadIdx.x;
    const int n0 = blockIdx.x * 64;
    const int nvalid = min(64, N_NODES - n0);

    for (int i = tid; i < 48 * 72; i += 256) wot[i] = 0;
    if (tid < 48) bos[tid] = (tid < OUT_F) ? bo[tid] : 0.0f;
    __syncthreads();
    for (int i = tid; i < HID * OUT_F; i += 256) {
        int k = i / OUT_F, j = i % OUT_F;       // Wo[k][j]
        wot[j * 72 + k] = f2bf(Wo[i]);
    }

    const int feat = tid & 63;
    const float invN = 1.0f / (float)N_NODES;
    float mm = sums[feat] * invN;
    float vv = sums[HID + feat] * invN - mm * mm;
    float inv = rsqrtf(vv + BN_EPS);
    float g = gamma[feat], b = beta[feat];
    for (int idx = tid; idx < 64 * HID; idx += 256) {
        int node = idx >> 6;
        float h = 0.0f;
        if (node < nvalid) {
            int gi = (n0 + node) * HID + feat;
            float a = agg[gi];
            h = hprev[gi] + fmaxf(g * (a - mm) * inv + b, 0.0f);
        }
        hb[node * 72 + feat] = f2bf(h);
    }
    __syncthreads();

    const int lane = tid & 63, wid = tid >> 6;
    const int ml = lane & 15, gl = lane >> 4;
    const int r0 = wid * 16;

    short8 A0 = *(const short8*)&hb[(r0 + ml) * 72 + gl * 8];
    short8 A1 = *(const short8*)&hb[(r0 + ml) * 72 + 32 + gl * 8];

    #pragma unroll
    for (int ct = 0; ct < 3; ++ct) {
        short8 b0 = *(const short8*)&wot[(ct * 16 + ml) * 72 + gl * 8];
        short8 b1 = *(const short8*)&wot[(ct * 16 + ml) * 72 + 32 + gl * 8];
        f32x4 z = {0.f, 0.f, 0.f, 0.f};
        z = __builtin_amdgcn_mfma_f32_16x16x32_bf16(A0, b0, z, 0, 0, 0);
        z = __builtin_amdgcn_mfma_f32_16x16x32_bf16(A1, b1, z, 0, 0, 0);
        int col = ct * 16 + ml;
        #pragma unroll
        for (int reg = 0; reg < 4; ++reg) {
            int node = n0 + r0 + gl * 4 + reg;
            if (node < N_NODES && col < OUT_F)
                out[(size_t)node * OUT_F + col] = z[reg] + bos[col];
        }
    }
}

extern "C" void kernel_launch(void* const* d_in, const int* in_sizes, int n_in,
                              void* d_out, int out_size, void* d_ws, size_t ws_size,
                              hipStream_t stream) {
    const float* x     = (const float*)d_in[0];
    const int*   ei    = (const int*)  d_in[1];   // [2, E]: row then col
    const float* Wi    = (const float*)d_in[2];
    const float* bi    = (const float*)d_in[3];
    const float* w1    = (const float*)d_in[4];
    const float* w2    = (const float*)d_in[5];
    const float* gamma = (const float*)d_in[6];
    const float* beta  = (const float*)d_in[7];
    const float* Wo    = (const float*)d_in[8];
    const float* bo    = (const float*)d_in[9];
    float* out = (float*)d_out;

    char* ws = (char*)d_ws;
    const size_t NH  = (size_t)N_NODES * HID * sizeof(float);          // 25.6 MB
    const size_t NHB = (size_t)N_NODES * HID * sizeof(unsigned short); // 12.8 MB
    size_t off = 0;
    auto alloc = [&](size_t bytes) { void* p = ws + off; off += (bytes + 255) & ~255UL; return p; };
    int*   degInt    = (int*)  alloc(N_NODES * sizeof(int));
    int*   tmpIncl   = (int*)  alloc(N_NODES * sizeof(int));
    int*   blockSums = (int*)  alloc(SCAN_BLOCKS * sizeof(int));
    int*   blockOff  = (int*)  alloc(SCAN_BLOCKS * sizeof(int));
    int*   rowOff    = (int*)  alloc((N_NODES + 1) * sizeof(int));
    int*   cursor    = (int*)  alloc(N_NODES * sizeof(int));
    int*   srow      = (int*)  alloc(E_EDGES * sizeof(int));
    float* dinv      = (float*)alloc(N_NODES * sizeof(float));
    unsigned short* sscaled = (unsigned short*)alloc(NHB);
    unsigned short* h0bf    = (unsigned short*)alloc(NHB);
    float* agg       = (float*)alloc(NH);
    float* hprev     = (float*)alloc(NH);
    float* sums      = (float*)alloc(LAYERS * 128 * sizeof(float));
    (void)ws_size; (void)in_sizes; (void)n_in; (void)out_size;

    hipMemsetAsync(degInt, 0, N_NODES * sizeof(int), stream);
    hipMemsetAsync(sums, 0, LAYERS * 128 * sizeof(float), stream);

    k_deg_count<<<(E_EDGES + 255) / 256, 256, 0, stream>>>(ei + E_EDGES, degInt);
    k_scanA<<<SCAN_BLOCKS, 256, 0, stream>>>(degInt, tmpIncl, blockSums);
    k_scanB<<<1, 512, 0, stream>>>(blockSums, blockOff);
    k_scanC<<<SCAN_BLOCKS, 256, 0, stream>>>(degInt, tmpIncl, blockOff,
                                             rowOff, cursor, dinv);
    k_fill<<<(E_EDGES + 255) / 256, 256, 0, stream>>>(ei, cursor, srow);

    k_input<<<TILE_BLOCKS, 256, 0, stream>>>(x, Wi, bi, h0bf, hprev);

    for (int l = 0; l < LAYERS; ++l) {
        const float* sums_prev = (l > 0) ? (sums + (l - 1) * 128) : sums;
        const float* gm        = (l > 0) ? (gamma + (l - 1) * HID) : gamma;
        const float* bt        = (l > 0) ? (beta  + (l - 1) * HID) : beta;
        k_layerA<<<TILE_BLOCKS, 256, 0, stream>>>(hprev, h0bf, agg,
                                                  sums_prev, gm, bt, (l > 0),
                                                  w1 + (size_t)l * HID * HID,
                                                  w2 + (size_t)l * HID * HID,
                                                  dinv, sscaled);
        k_gather<<<2048, 256, 0, stream>>>(rowOff, srow, dinv, sscaled, agg,
                                           sums + l * 128);
    }

    k_out<<<TILE_BLOCKS, 256, 0, stream>>>(hprev, agg, sums + 3 * 128,
                                           gamma + 3 * HID, beta + 3 * HID, Wo, bo, out);
}